// Round 11
// baseline (295902.295 us; speedup 1.0000x reference)
//
#include <hip/hip_runtime.h>
#include <math.h>

#define T_STEPS 22550
#define NWG 32
#define NTHR 256

typedef unsigned long long ull;

// ---- u64 slot indices ----
#define SL_PRE  0                 // [512 elems][4]: pr, pz, pna, hn (pre-activations)
#define SL_PLC  2048              // [32 producers][256] partial c-logits
#define SL_PLF  10240             // [32 producers][256] partial f-logits
#define SL_END  18432

// ---- float offsets in ws ----
#define OF_SLOT  64
#define OF_AFTER (OF_SLOT + SL_END*2)
#define OF_BUFA  OF_AFTER                 // conv stage0 out [128][412]
#define OF_BUFB  (OF_BUFA + 128*412)      // conv stage1 out [128][2052]
#define OF_COND  (OF_BUFB + 128*2052)     // cond [T][128]

__global__ void k_init(float* ws){
  int i = blockIdx.x*blockDim.x + threadIdx.x;
  ull* sl = (ull*)(ws + OF_SLOT);
  if (i < SL_END) __hip_atomic_store(&sl[i], 0ULL, __ATOMIC_RELAXED, __HIP_MEMORY_SCOPE_AGENT);
}

// transposed conv (lhs_dilation=sc), padding e, then relu.
// mode 0: y[c][j]; mode 1: write cond[t=j-1][c] (crop [1:-1], transpose)
__global__ void k_upconv(const float* __restrict__ x, int instride, int inoff,
                         const float* __restrict__ w, const float* __restrict__ b,
                         float* __restrict__ y, int Cin, int Lin, int K, int sc, int e,
                         int Lout, int mode)
{
  int j = blockIdx.x*blockDim.x + threadIdx.x;
  int c = blockIdx.y;
  if (j >= Lout) return;
  float acc = b[c];
  int kstart = ((e - j) % sc + sc) % sc;
  for (int i = 0; i < Cin; ++i){
    const float* wci = w + (c*Cin + i)*K;
    const float* xi  = x + i*instride + inoff;
    for (int k = kstart; k < K; k += sc){
      int qd = j - e + k;
      if (qd >= 0){
        int qq = qd / sc;
        if (qq < Lin) acc += wci[k]*xi[qq];
      }
    }
  }
  acc = fmaxf(acc, 0.f);
  if (mode == 0) y[c*Lout + j] = acc;
  else { int t = j - 1; if (t >= 0 && t < T_STEPS) y[t*128 + c] = acc; }
}

__device__ __forceinline__ float sigm(float x){ return 1.f/(1.f + expf(-x)); }

__device__ __forceinline__ void pub64(ull* p, ull pk){
  (void)__hip_atomic_exchange(p, pk, __ATOMIC_RELAXED, __HIP_MEMORY_SCOPE_AGENT);
}
__device__ __forceinline__ ull ld64(ull* p){
  return __hip_atomic_load(p, __ATOMIC_RELAXED, __HIP_MEMORY_SCOPE_AGENT);
}
__device__ __forceinline__ ull pack_data(float v, unsigned tag){
  return ((ull)__float_as_uint(v) << 32) | (ull)tag;
}

__launch_bounds__(NTHR)
__global__ void k_wavernn(const float* __restrict__ Wx, const float* __restrict__ bx,
                          const float* __restrict__ Wh, const float* __restrict__ bh,
                          const float* __restrict__ O1w, const float* __restrict__ O1b,
                          const float* __restrict__ O2w, const float* __restrict__ O2b,
                          const float* __restrict__ O3w, const float* __restrict__ O3b,
                          const float* __restrict__ O4w, const float* __restrict__ O4b,
                          float* ws, float* __restrict__ out)
{
  __shared__ __align__(16) float h_s[512];       // h state (locally maintained, all elems)
  __shared__ __align__(16) float m_s[128];       // cond row for WX(t+1)
  __shared__ __align__(16) float h1_s[256];
  __shared__ __align__(16) float logit_s[256];
  __shared__ __align__(16) float pr_s[512], pz_s[512], pna_s[512], hn_s[512];
  __shared__ __align__(16) float w1r_s[512], w1z_s[512], w1n_s[512];
  __shared__ __align__(16) float w2r_s[512], w2z_s[512], w2n_s[512];
  __shared__ float o1own_s[16], o3own_s[16];
  __shared__ float hg_s[48], xgb_s[48];
  __shared__ float sc_s[8];                      // [0]=f_val [2]=c_cat [3]=c_new
  __shared__ float wc0_s[48], bx_s[48], bh_s[48];

  const int tid = threadIdx.x, g = blockIdx.x;
  ull* sl = (ull*)(ws + OF_SLOT);
  const float* cond = ws + OF_COND;
  float* out_samp = out;
  float* out_log  = out + T_STEPS;

  // ---- static preloads ----
  if (tid < 48){
    int row = (tid>>4)*512 + g + 32*(tid&15);
    wc0_s[tid] = Wx[(size_t)row*131 + 0];
    bx_s[tid]  = bx[row];
    bh_s[tid]  = bh[row];
  }
  for (int e = tid; e < 512; e += NTHR){
    w1r_s[e] = Wx[(size_t)e*131 + 1];
    w1z_s[e] = Wx[(size_t)(512+e)*131 + 1];
    w1n_s[e] = Wx[(size_t)(1024+e)*131 + 1];
    w2r_s[e] = Wx[(size_t)e*131 + 2];
    w2z_s[e] = Wx[(size_t)(512+e)*131 + 2];
    w2n_s[e] = Wx[(size_t)(1024+e)*131 + 2];
  }
  // O1/O3 row weights: WG owns rows {g+32*m16}, 16 lanes/row, 16 contiguous cols/lane
  const int m16 = tid>>4, c16 = tid&15;
  const int rowO1 = g + 32*m16;
  float wO1r[16], wO3r[16];
  #pragma unroll
  for (int k=0;k<16;++k){
    wO1r[k] = O1w[(size_t)rowO1*256 + c16*16 + k];
    wO3r[k] = O3w[(size_t)rowO1*256 + c16*16 + k];
  }
  const float bO1r = O1b[rowO1], bO3r = O3b[rowO1];
  // O2/O4 column slices: thread tid owns logit tid; columns = own o-rows {g+32m}
  float wPC[16], wPF[16];
  #pragma unroll
  for (int m=0;m<16;++m){
    wPC[m] = O2w[(size_t)tid*512 + g + 32*m];
    wPF[m] = O4w[(size_t)tid*512 + g + 32*m];
  }
  const float cbO2 = O2b[tid], cbO4 = O4b[tid];

  h_s[tid] = 0.f; h_s[tid+256] = 0.f;
  if (tid < 128) m_s[tid] = cond[tid];             // m(0) for bootstrap WX
  if (tid == 0){ sc_s[0] = 0.f; sc_s[2] = 0.f; sc_s[3] = 0.f; }
  __syncthreads();

  // xgb = Wx[:,3:]@m + bx    (48 rows x 4 lanes)
  #define COMPUTE_WX() do { \
    if (tid < 192){ \
      const int li_ = tid>>2, q_ = tid&3; \
      const int row_ = (li_>>4)*512 + g + 32*(li_&15); \
      const float* WxR = Wx + (size_t)row_*131 + 3; \
      float aX = 0.f; \
      _Pragma("unroll") \
      for (int kk=0; kk<32; ++kk){ \
        int f_ = q_*32 + ((kk + 8*q_) & 31); \
        aX += WxR[f_]*m_s[f_]; \
      } \
      aX += __shfl_xor(aX,1); aX += __shfl_xor(aX,2); \
      if (q_ == 0) xgb_s[li_] = aX + bx_s[li_]; \
    } } while(0)

  // hg = Wh@h + bh           (48 rows x 4 lanes, bank-swizzled LDS reads of h_s)
  #define COMPUTE_WH() do { \
    if (tid < 192){ \
      const int li_ = tid>>2, q_ = tid&3; \
      const int row_ = (li_>>4)*512 + g + 32*(li_&15); \
      const float4* W4 = (const float4*)(Wh + (size_t)row_*512); \
      const float4* H4 = (const float4*)h_s; \
      float aH = 0.f; \
      _Pragma("unroll") \
      for (int kk=0; kk<32; ++kk){ \
        int f_ = q_*32 + ((kk + 2*q_) & 31); \
        float4 w = W4[f_], v = H4[f_]; \
        aH += w.x*v.x + w.y*v.y + w.z*v.z + w.w*v.w; \
      } \
      aH += __shfl_xor(aH,1); aH += __shfl_xor(aH,2); \
      if (q_ == 0) hg_s[li_] = aH + bh_s[li_]; \
    } } while(0)

  // publish own 16 elems' pre-gates: pr, pz, pna, hn  (64 slots, tid<64)
  #define PUB_PREGATES(TAGP) do { \
    if (tid < 64){ \
      const int i_ = tid>>2, c_ = tid&3; \
      const int e_ = g + 32*i_; \
      const float c0_ = sc_s[3]; \
      float v_; \
      if (c_ == 0)      v_ = xgb_s[i_]    + c0_*wc0_s[i_]    + hg_s[i_]; \
      else if (c_ == 1) v_ = xgb_s[16+i_] + c0_*wc0_s[16+i_] + hg_s[16+i_]; \
      else if (c_ == 2) v_ = xgb_s[32+i_] + c0_*wc0_s[32+i_]; \
      else              v_ = hg_s[32+i_]; \
      pub64(&sl[SL_PRE + e_*4 + c_], pack_data(v_, (TAGP))); \
    } } while(0)

  // fat gather: 32 slabs x 256, issue-then-check batched re-poll, fixed-order sum
  #define FAT_GATHER(BASE, BIAS) do { \
    ull pk_[32]; \
    _Pragma("unroll") \
    for (int g2=0; g2<32; ++g2) pk_[g2] = ld64(&sl[(BASE) + g2*256 + tid]); \
    for (;;){ \
      bool all_ = true; \
      _Pragma("unroll") \
      for (int g2=0; g2<32; ++g2) if ((unsigned)pk_[g2] != tag) all_ = false; \
      if (all_) break; \
      _Pragma("unroll") \
      for (int g2=0; g2<32; ++g2) \
        if ((unsigned)pk_[g2] != tag) pk_[g2] = ld64(&sl[(BASE) + g2*256 + tid]); \
    } \
    float s_ = (BIAS); \
    _Pragma("unroll") \
    for (int g2=0; g2<32; ++g2) s_ += __uint_as_float((unsigned)(pk_[g2] >> 32)); \
    logit_s[tid] = s_; \
  } while(0)

  // bootstrap: h=0 -> hg=bh; xgb from m(0); c_val(0)=0 -> publish pregates tag 1
  COMPUTE_WX();
  if (tid < 48) hg_s[tid] = bh_s[tid];
  __syncthreads();
  PUB_PREGATES(1u);

  for (int t = 0; t < T_STEPS; ++t){
    const unsigned tag = (unsigned)(t + 1);

    // ---- (A) gather pre-gates(t) [batched re-poll]; load m(t+1) ----
    {
      ull pk[8];
      #pragma unroll
      for (int c=0;c<4;++c){
        pk[c]   = ld64(&sl[SL_PRE + tid*4 + c]);
        pk[4+c] = ld64(&sl[SL_PRE + (tid+256)*4 + c]);
      }
      for (;;){
        bool all = true;
        #pragma unroll
        for (int i=0;i<8;++i) if ((unsigned)pk[i] != tag) all = false;
        if (all) break;
        #pragma unroll
        for (int i=0;i<8;++i)
          if ((unsigned)pk[i] != tag){
            int slot = (i<4) ? (tid*4 + i) : ((tid+256)*4 + (i-4));
            pk[i] = ld64(&sl[SL_PRE + slot]);
          }
      }
      pr_s[tid]      = __uint_as_float((unsigned)(pk[0] >> 32));
      pz_s[tid]      = __uint_as_float((unsigned)(pk[1] >> 32));
      pna_s[tid]     = __uint_as_float((unsigned)(pk[2] >> 32));
      hn_s[tid]      = __uint_as_float((unsigned)(pk[3] >> 32));
      pr_s[tid+256]  = __uint_as_float((unsigned)(pk[4] >> 32));
      pz_s[tid+256]  = __uint_as_float((unsigned)(pk[5] >> 32));
      pna_s[tid+256] = __uint_as_float((unsigned)(pk[6] >> 32));
      hn_s[tid+256]  = __uint_as_float((unsigned)(pk[7] >> 32));
    }
    if (tid < 128 && t + 1 < T_STEPS) m_s[tid] = cond[(size_t)(t+1)*128 + tid];
    __syncthreads();

    // ---- (B) h1 local for lower 256 elems (bit-identical on all WGs) ----
    {
      const float f = sc_s[0];
      float r = sigm(pr_s[tid]  + f*w1r_s[tid]);
      float z = sigm(pz_s[tid]  + f*w1z_s[tid]);
      float n = tanhf(pna_s[tid] + f*w1n_s[tid] + r*hn_s[tid]);
      h1_s[tid] = (1.f - z)*n + z*h_s[tid];
    }
    __syncthreads();

    // ---- (C) own 16 o1 rows -> partial c-logits publish ----
    {
      float acc = 0.f;
      #pragma unroll
      for (int k=0;k<16;++k) acc += wO1r[k]*h1_s[c16*16 + k];
      acc += __shfl_xor(acc,1); acc += __shfl_xor(acc,2);
      acc += __shfl_xor(acc,4); acc += __shfl_xor(acc,8);
      if (c16 == 0) o1own_s[m16] = fmaxf(acc + bO1r, 0.f);
    }
    __syncthreads();
    {
      float s = 0.f;
      #pragma unroll
      for (int m=0;m<16;++m) s += wPC[m]*o1own_s[m];
      pub64(&sl[SL_PLC + g*256 + tid], pack_data(s, tag));
    }

    // ---- (D) WX(t+1) fills part of the plc trip ----
    COMPUTE_WX();

    // ---- (E) fat gather plc -> full c-logits; own log slice; local argmax -> c ----
    FAT_GATHER(SL_PLC, cbO2);
    __syncthreads();
    if (tid < 8) out_log[(size_t)t*512 + g*8 + tid] = logit_s[g*8 + tid];
    if (tid < 64){
      float bv = logit_s[tid]; int bi = tid;
      #pragma unroll
      for (int j=1;j<4;++j){ float v = logit_s[tid + 64*j]; if (v > bv){ bv = v; bi = tid + 64*j; } }
      #pragma unroll
      for (int off=32; off>=1; off>>=1){
        float ov = __shfl_xor(bv,off); int oi = __shfl_xor(bi,off);
        if (ov > bv || (ov == bv && oi < bi)){ bv = ov; bi = oi; }
      }
      if (tid == 0){ sc_s[2] = (float)bi; sc_s[3] = (float)bi/127.5f - 1.f; }
    }
    __syncthreads();

    // ---- (F) h2 local for ALL 512 elems (bit-identical on all WGs) ----
    {
      const float f = sc_s[0], cn = sc_s[3];
      #pragma unroll
      for (int hh=0; hh<2; ++hh){
        int e = tid + 256*hh;
        float r = sigm(pr_s[e]  + f*w1r_s[e] + cn*w2r_s[e]);
        float z = sigm(pz_s[e]  + f*w1z_s[e] + cn*w2z_s[e]);
        float n = tanhf(pna_s[e] + f*w1n_s[e] + cn*w2n_s[e] + r*hn_s[e]);
        h_s[e] = (1.f - z)*n + z*h_s[e];
      }
    }
    __syncthreads();

    // ---- (G) own 16 o3 rows from h2 upper half -> partial f-logits publish ----
    {
      float acc = 0.f;
      #pragma unroll
      for (int k=0;k<16;++k) acc += wO3r[k]*h_s[256 + c16*16 + k];
      acc += __shfl_xor(acc,1); acc += __shfl_xor(acc,2);
      acc += __shfl_xor(acc,4); acc += __shfl_xor(acc,8);
      if (c16 == 0) o3own_s[m16] = fmaxf(acc + bO3r, 0.f);
    }
    __syncthreads();
    {
      float s = 0.f;
      #pragma unroll
      for (int m=0;m<16;++m) s += wPF[m]*o3own_s[m];
      pub64(&sl[SL_PLF + g*256 + tid], pack_data(s, tag));
    }

    // ---- (H) WH(t+1) from local h2; publish pre-gates(t+1) — fills the plf trip ----
    COMPUTE_WH();
    __syncthreads();
    if (t + 1 < T_STEPS) PUB_PREGATES((unsigned)(t + 2));

    // ---- (I) fat gather plf -> full f-logits; own slice; argmax -> f; sample ----
    FAT_GATHER(SL_PLF, cbO4);
    __syncthreads();
    if (tid < 8) out_log[(size_t)t*512 + 256 + g*8 + tid] = logit_s[g*8 + tid];
    if (tid < 64){
      float bv = logit_s[tid]; int bi = tid;
      #pragma unroll
      for (int j=1;j<4;++j){ float v = logit_s[tid + 64*j]; if (v > bv){ bv = v; bi = tid + 64*j; } }
      #pragma unroll
      for (int off=32; off>=1; off>>=1){
        float ov = __shfl_xor(bv,off); int oi = __shfl_xor(bi,off);
        if (ov > bv || (ov == bv && oi < bi)){ bv = ov; bi = oi; }
      }
      if (tid == 0){
        sc_s[0] = (float)bi/127.5f - 1.f;                 // f carry for step t+1
        if (g == 0) out_samp[t] = (sc_s[2]*256.f + (float)bi)/32767.5f - 1.f;
      }
    }
    // loop-top (A) __syncthreads() protects sc_s[0] and pr_s overwrites
  }
}

extern "C" void kernel_launch(void* const* d_in, const int* in_sizes, int n_in,
                              void* d_out, int out_size, void* d_ws, size_t ws_size,
                              hipStream_t stream)
{
  const float* mels  = (const float*)d_in[0];
  const float* up_w0 = (const float*)d_in[1]; const float* up_b0 = (const float*)d_in[2];
  const float* up_w1 = (const float*)d_in[3]; const float* up_b1 = (const float*)d_in[4];
  const float* up_w2 = (const float*)d_in[5]; const float* up_b2 = (const float*)d_in[6];
  const float* Wx  = (const float*)d_in[7];  const float* bx  = (const float*)d_in[8];
  const float* Wh  = (const float*)d_in[9];  const float* bh  = (const float*)d_in[10];
  const float* O1w = (const float*)d_in[11]; const float* O1b = (const float*)d_in[12];
  const float* O2w = (const float*)d_in[13]; const float* O2b = (const float*)d_in[14];
  const float* O3w = (const float*)d_in[15]; const float* O3b = (const float*)d_in[16];
  const float* O4w = (const float*)d_in[17]; const float* O4b = (const float*)d_in[18];
  float* ws  = (float*)d_ws;
  float* out = (float*)d_out;

  k_init<<<(SL_END + 255)/256, 256, 0, stream>>>(ws);

  // upsample: 84 -> 412 -> 2052 -> 22552 (crop [1:-1] -> cond[22550][128])
  k_upconv<<<dim3((412  +127)/128, 128), 128, 0, stream>>>(mels,        86,   1, up_w0, up_b0,
            ws+OF_BUFA,  80,   84, 11,  5, 3,   412, 0);
  k_upconv<<<dim3((2052 +127)/128, 128), 128, 0, stream>>>(ws+OF_BUFA, 412,   0, up_w1, up_b1,
            ws+OF_BUFB, 128,  412, 11,  5, 3,  2052, 0);
  k_upconv<<<dim3((22552+127)/128, 128), 128, 0, stream>>>(ws+OF_BUFB, 2052,  0, up_w2, up_b2,
            ws+OF_COND, 128, 2052, 23, 11, 6, 22552, 1);

  k_wavernn<<<NWG, NTHR, 0, stream>>>(Wx, bx, Wh, bh, O1w, O1b, O2w, O2b,
                                      O3w, O3b, O4w, O4b, ws, out);
}